// Round 1
// baseline (8168.332 us; speedup 1.0000x reference)
//
#include <hip/hip_runtime.h>
#include <math.h>

#define NRAYS  16384
#define NSEG   32
#define DIM    128
#define DFF    512
#define NHEADS 4
#define DHEAD  32
#define ENCD   72
#define PX     132   // pitch (floats) for 128-wide LDS tiles (16B aligned, bank-skewed)
#define PE     76    // pitch for 72-wide encoding tile
#define PS     36    // pitch for 32-wide score rows
#define SEGL   0.1875f

__device__ __forceinline__ float4 ld4(const float* p) { return *(const float4*)p; }

// OUT[0..31][0..127] (pitch PX) (+)= A[32 x K](pitch pa) @ W[K x 128](row-major ldw) (+ bias)
template<bool ACC, bool RELU>
__device__ __forceinline__ void gemm128(const float* __restrict__ A, int pa, int K,
                                        const float* __restrict__ Wg, int ldw,
                                        const float* __restrict__ bias,
                                        float* __restrict__ OUT, int tid)
{
    const int c4 = (tid & 31) * 4;       // output column start
    const int s0 = (tid >> 5) * 4;       // output row start (4 rows per thread)
    float acc[4][4];
    float bv[4] = {0.f, 0.f, 0.f, 0.f};
    if (bias) { float4 b = ld4(bias + c4); bv[0]=b.x; bv[1]=b.y; bv[2]=b.z; bv[3]=b.w; }
#pragma unroll
    for (int i = 0; i < 4; ++i) {
        if (ACC) {
            float4 o = ld4(OUT + (s0+i)*PX + c4);
            acc[i][0]=o.x+bv[0]; acc[i][1]=o.y+bv[1]; acc[i][2]=o.z+bv[2]; acc[i][3]=o.w+bv[3];
        } else {
            acc[i][0]=bv[0]; acc[i][1]=bv[1]; acc[i][2]=bv[2]; acc[i][3]=bv[3];
        }
    }
    for (int k = 0; k < K; k += 4) {
        float wr[4][4];
        *(float4*)&wr[0][0] = ld4(Wg + (k+0)*ldw + c4);
        *(float4*)&wr[1][0] = ld4(Wg + (k+1)*ldw + c4);
        *(float4*)&wr[2][0] = ld4(Wg + (k+2)*ldw + c4);
        *(float4*)&wr[3][0] = ld4(Wg + (k+3)*ldw + c4);
#pragma unroll
        for (int i = 0; i < 4; ++i) {
            float av[4];
            *(float4*)av = ld4(A + (s0+i)*pa + k);
#pragma unroll
            for (int kk = 0; kk < 4; ++kk)
#pragma unroll
                for (int jj = 0; jj < 4; ++jj)
                    acc[i][jj] = fmaf(av[kk], wr[kk][jj], acc[i][jj]);
        }
    }
#pragma unroll
    for (int i = 0; i < 4; ++i) {
        float vx=acc[i][0], vy=acc[i][1], vz=acc[i][2], vw=acc[i][3];
        if (RELU) { vx=fmaxf(vx,0.f); vy=fmaxf(vy,0.f); vz=fmaxf(vz,0.f); vw=fmaxf(vw,0.f); }
        *(float4*)(OUT + (s0+i)*PX + c4) = make_float4(vx, vy, vz, vw);
    }
}

// OUTb = LN(IN) * sc + bi   (population variance, eps 1e-5). Contains one __syncthreads().
__device__ __forceinline__ void layer_norm(const float* __restrict__ IN, float* __restrict__ OUTb,
                                           const float* __restrict__ sc, const float* __restrict__ bi,
                                           int tid, float* MU, float* RS)
{
    const int s = tid >> 3, p = tid & 7;
    const float* row = IN + s*PX + p*16;
    float sum = 0.f, sq = 0.f;
#pragma unroll
    for (int j = 0; j < 16; ++j) { float v = row[j]; sum += v; sq = fmaf(v, v, sq); }
#pragma unroll
    for (int off = 1; off < 8; off <<= 1) { sum += __shfl_xor(sum, off); sq += __shfl_xor(sq, off); }
    if (p == 0) {
        float mu  = sum * 0.0078125f;
        float var = sq * 0.0078125f - mu*mu;
        MU[s] = mu; RS[s] = rsqrtf(var + 1e-5f);
    }
    __syncthreads();
#pragma unroll
    for (int rep = 0; rep < 16; ++rep) {
        int e = rep*256 + tid;
        int s2 = e >> 7, d = e & 127;
        OUTb[s2*PX + d] = (IN[s2*PX + d] - MU[s2]) * RS[s2] * sc[d] + bi[d];
    }
}

__global__ __launch_bounds__(256, 1)
void ray_tf_kernel(const float* __restrict__ points,
                   const float* __restrict__ W_up, const float* __restrict__ b_up,
                   const float* __restrict__ ln1_s, const float* __restrict__ ln1_b,
                   const float* __restrict__ Wq, const float* __restrict__ Wk,
                   const float* __restrict__ Wv, const float* __restrict__ Wo,
                   const float* __restrict__ ln2_s, const float* __restrict__ ln2_b,
                   const float* __restrict__ W1, const float* __restrict__ b1,
                   const float* __restrict__ W2, const float* __restrict__ b2,
                   const float* __restrict__ w_pool,
                   const float* __restrict__ W_hit, const float* __restrict__ b_hit,
                   const float* __restrict__ W_dc, const float* __restrict__ b_dc,
                   const float* __restrict__ W_dv, const float* __restrict__ b_dv,
                   float* __restrict__ out)
{
    __shared__ float X [NSEG*PX];
    __shared__ float Hh[NSEG*PX];
    __shared__ float Qb[NSEG*PX];
    __shared__ float Kb[NSEG*PX];
    __shared__ float Vb[NSEG*PX];
    __shared__ float SH[NSEG*PS];
    __shared__ float MU[NSEG], RS[NSEG], LG[NSEG], SCC[NSEG], SCV[NSEG], POOL[DIM];

    const int tid = threadIdx.x;
    const int r   = blockIdx.x;

    // ---- ray geometry (every thread, block-uniform) ----
    const float ox = points[r*6+0], oy = points[r*6+1], oz = points[r*6+2];
    float dx = points[r*6+3] - ox, dy = points[r*6+4] - oy, dz = points[r*6+5] - oz;
    const float dn = sqrtf(dx*dx + dy*dy + dz*dz);
    dx /= dn; dy /= dn; dz /= dn;
    const float bq = ox*dx + oy*dy + oz*dz;
    const float cq = ox*ox + oy*oy + oz*oz - 9.0f;
    const float sq = sqrtf(fmaxf(bq*bq - cq, 0.0f));
    const float t1 = -bq - sq, t2 = -bq + sq;
    int n_left = 0;
#pragma unroll
    for (int j = 0; j < NSEG; ++j) {
        float tj = t1 + (float)j * SEGL;   // mul exact, single add-round: matches linspace*6+t1
        n_left += (tj < t2) ? 1 : 0;
    }

    // ---- positional encoding -> Hh (pitch PE) ----
    for (int e = tid; e < NSEG*ENCD; e += 256) {
        int s = e / ENCD;
        int c = e - s*ENCD;
        int ep = c / 36;
        int rem = c - ep*36;
        int coord = rem / 12;
        int u = rem - coord*12;
        int jj = s + ep;
        float tj = t1 + (float)jj * SEGL;
        float oc = (coord == 0) ? ox : ((coord == 1) ? oy : oz);
        float vc = (coord == 0) ? dx : ((coord == 1) ? dy : dz);
        float pv = (oc + vc*tj) / 3.0f;
        if (s >= n_left) pv = 0.0f;
        int f = (u < 6) ? u : (u - 6);
        float ang = pv * (3.14159265358979323846f * (float)(1 << f));
        Hh[s*PE + c] = (u < 6) ? __sinf(ang) : __cosf(ang);
    }
    __syncthreads();

    // ---- x = enc @ W_up + b_up ----
    gemm128<false,false>(Hh, PE, ENCD, W_up, DIM, b_up, X, tid);
    __syncthreads();

    const float scale = 0.17677669529663687f;  // 1/sqrt(32)

    for (int l = 0; l < 2; ++l) {
        // LN1
        layer_norm(X, Hh, ln1_s + l*DIM, ln1_b + l*DIM, tid, MU, RS);
        __syncthreads();
        // Q, K, V
        gemm128<false,false>(Hh, PX, DIM, Wq + l*DIM*DIM, DIM, nullptr, Qb, tid);
        gemm128<false,false>(Hh, PX, DIM, Wk + l*DIM*DIM, DIM, nullptr, Kb, tid);
        gemm128<false,false>(Hh, PX, DIM, Wv + l*DIM*DIM, DIM, nullptr, Vb, tid);
        __syncthreads();

        for (int h = 0; h < NHEADS; ++h) {
            { // scores: SH[i][j] = scale * q[i]·k[j]
                const int i = tid >> 3, jc = tid & 7;
                float a0=0.f, a1=0.f, a2=0.f, a3=0.f;
                const float* qrow = Qb + i*PX + h*DHEAD;
                const float* kbase = Kb + h*DHEAD;
#pragma unroll 8
                for (int d = 0; d < DHEAD; ++d) {
                    float qv = qrow[d];
                    a0 = fmaf(qv, kbase[(jc*4+0)*PX + d], a0);
                    a1 = fmaf(qv, kbase[(jc*4+1)*PX + d], a1);
                    a2 = fmaf(qv, kbase[(jc*4+2)*PX + d], a2);
                    a3 = fmaf(qv, kbase[(jc*4+3)*PX + d], a3);
                }
                SH[i*PS + jc*4+0] = a0*scale;
                SH[i*PS + jc*4+1] = a1*scale;
                SH[i*PS + jc*4+2] = a2*scale;
                SH[i*PS + jc*4+3] = a3*scale;
            }
            __syncthreads();
            if (tid < NSEG) { // row softmax
                float m = -1e30f;
                for (int j = 0; j < NSEG; ++j) m = fmaxf(m, SH[tid*PS + j]);
                float ssum = 0.f;
                for (int j = 0; j < NSEG; ++j) { float e = __expf(SH[tid*PS + j] - m); SH[tid*PS + j] = e; ssum += e; }
                float inv = 1.0f / ssum;
                for (int j = 0; j < NSEG; ++j) SH[tid*PS + j] *= inv;
            }
            __syncthreads();
            { // o_h = att @ v_h  -> Hh columns [h*32, h*32+32)
                const int s = tid >> 3, dc = tid & 7;
                float o0=0.f, o1=0.f, o2=0.f, o3=0.f;
#pragma unroll 8
                for (int j = 0; j < NSEG; ++j) {
                    float a = SH[s*PS + j];
                    float4 vv = ld4(Vb + j*PX + h*DHEAD + dc*4);
                    o0 = fmaf(a, vv.x, o0); o1 = fmaf(a, vv.y, o1);
                    o2 = fmaf(a, vv.z, o2); o3 = fmaf(a, vv.w, o3);
                }
                *(float4*)(Hh + s*PX + h*DHEAD + dc*4) = make_float4(o0, o1, o2, o3);
            }
            __syncthreads();
        }
        // x += o @ Wo
        gemm128<true,false>(Hh, PX, DIM, Wo + l*DIM*DIM, DIM, nullptr, X, tid);
        __syncthreads();
        // LN2
        layer_norm(X, Hh, ln2_s + l*DIM, ln2_b + l*DIM, tid, MU, RS);
        __syncthreads();
        // FFN in 4 chunks of 128 ff-dims; Qb reused as scratch
        for (int c = 0; c < 4; ++c) {
            gemm128<false,true>(Hh, PX, DIM, W1 + l*DIM*DFF + c*DIM, DFF,
                                b1 + l*DFF + c*DIM, Qb, tid);
            __syncthreads();
            gemm128<true,false>(Qb, PX, DIM, W2 + l*DFF*DIM + c*DIM*DIM, DIM,
                                (c == 0) ? (b2 + l*DIM) : nullptr, X, tid);
            __syncthreads();
        }
    }

    // ---- pooling logits ----
    {
        const int s = tid >> 3, p = tid & 7;
        float acc = 0.f;
        const float* row = X + s*PX + p*16;
        const float* wp = w_pool + p*16;
#pragma unroll
        for (int j = 0; j < 16; ++j) acc = fmaf(row[j], wp[j], acc);
#pragma unroll
        for (int off = 1; off < 8; off <<= 1) acc += __shfl_xor(acc, off);
        if (p == 0) LG[s] = acc;
    }
    __syncthreads();
    // pooled vector (softmax over ALL 32 segments, matching reference)
    if (tid < DIM) {
        float m = -1e30f;
        for (int s = 0; s < NSEG; ++s) m = fmaxf(m, LG[s]);
        float ssum = 0.f;
        for (int s = 0; s < NSEG; ++s) ssum += __expf(LG[s] - m);
        float inv = 1.0f / ssum;
        float acc = 0.f;
        for (int s = 0; s < NSEG; ++s) acc = fmaf(__expf(LG[s] - m), X[s*PX + tid], acc);
        POOL[tid] = acc * inv;
    }
    // cls / val per-segment heads
    {
        const int s = tid >> 3, p = tid & 7;
        float c = 0.f, v = 0.f;
        const float* row = X + s*PX + p*16;
#pragma unroll
        for (int j = 0; j < 16; ++j) {
            float x = row[j];
            c = fmaf(x, W_dc[p*16 + j], c);
            v = fmaf(x, W_dv[p*16 + j], v);
        }
#pragma unroll
        for (int off = 1; off < 8; off <<= 1) { c += __shfl_xor(c, off); v += __shfl_xor(v, off); }
        if (p == 0) {
            SCC[s] = c + b_dc[0];
            SCV[s] = fminf(fmaxf(v + b_dv[0], 0.0f), 1.0f);
        }
    }
    __syncthreads();
    // hit = pooled @ W_hit + b_hit  (wave 0)
    if (tid < 64) {
        float v = POOL[tid]*W_hit[tid] + POOL[tid+64]*W_hit[tid+64];
#pragma unroll
        for (int off = 1; off < 64; off <<= 1) v += __shfl_xor(v, off);
        if (tid == 0) {
            float hv = v + b_hit[0];
            out[r] = (n_left == 0) ? -100.0f : hv;
        }
    }
    // argmax over masked cls; dist (order == identity so gidx == amax)
    if (tid == 255) {
        float best = -1e30f; int am = 0;
        for (int s = 0; s < NSEG; ++s) {
            if (s < n_left) {
                float cv = SCC[s];
                if (cv > best) { best = cv; am = s; }
            }
        }
        out[NRAYS + r] = SCV[am] + (float)am * SEGL + t1;
    }
}

extern "C" void kernel_launch(void* const* d_in, const int* in_sizes, int n_in,
                              void* d_out, int out_size, void* d_ws, size_t ws_size,
                              hipStream_t stream) {
    (void)in_sizes; (void)n_in; (void)d_ws; (void)ws_size; (void)out_size;
    const float* points = (const float*)d_in[0];
    const float* W_up   = (const float*)d_in[1];
    const float* b_up   = (const float*)d_in[2];
    const float* ln1_s  = (const float*)d_in[3];
    const float* ln1_b  = (const float*)d_in[4];
    const float* Wq     = (const float*)d_in[5];
    const float* Wk     = (const float*)d_in[6];
    const float* Wv     = (const float*)d_in[7];
    const float* Wo     = (const float*)d_in[8];
    const float* ln2_s  = (const float*)d_in[9];
    const float* ln2_b  = (const float*)d_in[10];
    const float* W1     = (const float*)d_in[11];
    const float* b1     = (const float*)d_in[12];
    const float* W2     = (const float*)d_in[13];
    const float* b2     = (const float*)d_in[14];
    const float* w_pool = (const float*)d_in[15];
    const float* W_hit  = (const float*)d_in[16];
    const float* b_hit  = (const float*)d_in[17];
    const float* W_dc   = (const float*)d_in[18];
    const float* b_dc   = (const float*)d_in[19];
    const float* W_dv   = (const float*)d_in[20];
    const float* b_dv   = (const float*)d_in[21];
    float* out = (float*)d_out;

    hipLaunchKernelGGL(ray_tf_kernel, dim3(NRAYS), dim3(256), 0, stream,
                       points, W_up, b_up, ln1_s, ln1_b, Wq, Wk, Wv, Wo,
                       ln2_s, ln2_b, W1, b1, W2, b2, w_pool,
                       W_hit, b_hit, W_dc, b_dc, W_dv, b_dv, out);
}

// Round 3
// 3284.111 us; speedup vs baseline: 2.4872x; 2.4872x over previous
//
#include <hip/hip_runtime.h>
#include <math.h>

#define NRAYS  16384
#define NSEG   32
#define DIM    128
#define DFF    512
#define ENCD   72
#define PXF    132       // fp32 residual pitch
#define PH     40        // bf16 per-head pitch (shorts): 80B rows, 16B-aligned
#define HL     (NSEG*PH) // hi->lo short offset inside a per-wave head tile pair
#define SEGL   0.1875f
#define LOOFF  405504    // hi->lo short offset in the weight fragment stream

typedef __attribute__((ext_vector_type(8))) short short8;
typedef __attribute__((ext_vector_type(4))) float f32x4;

__device__ __forceinline__ short f2b(float x) {   // fp32 -> bf16 RNE
    unsigned u = __float_as_uint(x);
    u += 0x7fff + ((u >> 16) & 1);
    return (short)(u >> 16);
}
__device__ __forceinline__ float b2f(short s) {
    return __uint_as_float(((unsigned)(unsigned short)s) << 16);
}
__device__ __forceinline__ void split2(float v, short &h, short &l) {
    h = f2b(v);
    l = f2b(v - b2f(h));
}

// ---------------- weight prep: fp32 -> bf16 hi/lo MFMA B-fragment streams ----------------
// hi stream: 24 gemms (2 layers x [Wq,Wk,Wv,Wo,W1c0..3,W2c0..3]) each 128x128 at g*16384,
// W_up (K padded 72->96) at 393216. lo stream mirrors hi at +LOOFF.
__global__ __launch_bounds__(256)
void prep_weights(const float* __restrict__ W_up, const float* __restrict__ Wq,
                  const float* __restrict__ Wk, const float* __restrict__ Wv,
                  const float* __restrict__ Wo, const float* __restrict__ W1,
                  const float* __restrict__ W2, short* __restrict__ out)
{
    int t = blockIdx.x * 256 + threadIdx.x;
    int j    = t & 7;
    int lane = (t >> 3) & 63;
    int krow = ((lane >> 4) << 3) + j;
    int ncol = lane & 15;
    float v;
    if (t < 393216) {
        int f = (t >> 9) & 7;
        int w = (t >> 12) & 3;
        int g = t >> 14;
        int kk = f >> 1, c = f & 1;
        int k = kk * 32 + krow;
        int n = w * 32 + c * 16 + ncol;
        int l = g / 12, gi = g - l * 12;
        if (gi < 4) {
            const float* s4 = (gi == 0) ? Wq : (gi == 1) ? Wk : (gi == 2) ? Wv : Wo;
            v = s4[l * 16384 + k * 128 + n];
        } else if (gi < 8) {
            v = W1[l * 65536 + k * 512 + (gi - 4) * 128 + n];
        } else {
            v = W2[l * 65536 + ((gi - 8) * 128 + k) * 128 + n];
        }
    } else {
        int t2 = t - 393216;         // [0, 12288)
        int w = t2 / 3072;
        int rem = t2 - w * 3072;
        int f = rem >> 9;            // 0..5
        int kk = f >> 1, c = f & 1;
        int k = kk * 32 + krow;
        int n = w * 32 + c * 16 + ncol;
        v = (k < ENCD) ? W_up[k * 128 + n] : 0.0f;
    }
    short h, l2;
    split2(v, h, l2);
    out[t] = h;
    out[t + LOOFF] = l2;
}

// A-operand fragment from swizzled row-major [32][128] bf16 LDS tile
__device__ __forceinline__ short8 lds_afrag(const short* Abuf, int rt, int kk, int lane) {
    int row  = rt * 16 + (lane & 15);
    int byte = row * 256 + kk * 64 + ((lane >> 4) << 4);
    byte ^= (row & 7) << 4;
    return *(const short8*)((const char*)Abuf + byte);
}

#define MFMA(a,b,c) __builtin_amdgcn_mfma_f32_16x16x32_bf16((a),(b),(c),0,0,0)

// OUT(32x128) += A(32xK, hi/lo LDS tiles) @ B(hi/lo frag streams); bf16x3 emulation
template<int NK>
__device__ __forceinline__ void mfma_gemm3(const short* AbH, const short* AbL,
                                           const short* BwH, f32x4 acc[2][2], int lane) {
    const short* BwL = BwH + LOOFF;
#pragma unroll
    for (int kk = 0; kk < NK; ++kk) {
        short8 ah0 = lds_afrag(AbH, 0, kk, lane);
        short8 ah1 = lds_afrag(AbH, 1, kk, lane);
        short8 al0 = lds_afrag(AbL, 0, kk, lane);
        short8 al1 = lds_afrag(AbL, 1, kk, lane);
        short8 bh0 = *(const short8*)(BwH + ((kk * 2 + 0) * 64 + lane) * 8);
        short8 bh1 = *(const short8*)(BwH + ((kk * 2 + 1) * 64 + lane) * 8);
        short8 bl0 = *(const short8*)(BwL + ((kk * 2 + 0) * 64 + lane) * 8);
        short8 bl1 = *(const short8*)(BwL + ((kk * 2 + 1) * 64 + lane) * 8);
        acc[0][0] = MFMA(ah0, bh0, acc[0][0]);
        acc[1][0] = MFMA(ah1, bh0, acc[1][0]);
        acc[0][1] = MFMA(ah0, bh1, acc[0][1]);
        acc[1][1] = MFMA(ah1, bh1, acc[1][1]);
        acc[0][0] = MFMA(al0, bh0, acc[0][0]);
        acc[1][0] = MFMA(al1, bh0, acc[1][0]);
        acc[0][1] = MFMA(al0, bh1, acc[0][1]);
        acc[1][1] = MFMA(al1, bh1, acc[1][1]);
        acc[0][0] = MFMA(ah0, bl0, acc[0][0]);
        acc[1][0] = MFMA(ah1, bl0, acc[1][0]);
        acc[0][1] = MFMA(ah0, bl1, acc[0][1]);
        acc[1][1] = MFMA(ah1, bl1, acc[1][1]);
    }
}

// LayerNorm from fp32 X -> swizzled hi/lo bf16 A-tiles (sync-free: 8-thread shfl reduce)
__device__ __forceinline__ void ln_to_Ab(const float* Xs, const float* sc, const float* bi,
                                         short* AbH, short* AbL, int tid) {
    const int s = tid >> 3, p = tid & 7;
    const float* row = Xs + s * PXF + p * 16;
    float sum = 0.f, sq = 0.f;
#pragma unroll
    for (int j = 0; j < 16; ++j) { float v = row[j]; sum += v; sq = fmaf(v, v, sq); }
#pragma unroll
    for (int off = 1; off < 8; off <<= 1) { sum += __shfl_xor(sum, off); sq += __shfl_xor(sq, off); }
    float mu = sum * 0.0078125f;
    float rs = rsqrtf(sq * 0.0078125f - mu * mu + 1e-5f);
    short8 o0h, o1h, o0l, o1l;
#pragma unroll
    for (int j = 0; j < 8; ++j) {
        float v0 = (row[j]     - mu) * rs * sc[p * 16 + j]     + bi[p * 16 + j];
        float v1 = (row[j + 8] - mu) * rs * sc[p * 16 + 8 + j] + bi[p * 16 + 8 + j];
        short h, l;
        split2(v0, h, l); o0h[j] = h; o0l[j] = l;
        split2(v1, h, l); o1h[j] = h; o1l[j] = l;
    }
    int base = s * 256 + p * 32, swz = (s & 7) << 4;
    *(short8*)((char*)AbH + ((base)      ^ swz)) = o0h;
    *(short8*)((char*)AbH + ((base + 16) ^ swz)) = o1h;
    *(short8*)((char*)AbL + ((base)      ^ swz)) = o0l;
    *(short8*)((char*)AbL + ((base + 16) ^ swz)) = o1l;
}

__global__ __launch_bounds__(256)
void ray_tf_kernel(const float* __restrict__ points,
                   const float* __restrict__ b_up,
                   const float* __restrict__ ln1_s, const float* __restrict__ ln1_b,
                   const float* __restrict__ ln2_s, const float* __restrict__ ln2_b,
                   const float* __restrict__ b1, const float* __restrict__ b2,
                   const float* __restrict__ w_pool,
                   const float* __restrict__ W_hit, const float* __restrict__ b_hit,
                   const float* __restrict__ W_dc, const float* __restrict__ b_dc,
                   const float* __restrict__ W_dv, const float* __restrict__ b_dv,
                   const short* __restrict__ Wf,
                   float* __restrict__ out)
{
    __shared__ float X[NSEG * PXF];
    __shared__ short AbH[NSEG * DIM];
    __shared__ short AbL[NSEG * DIM];
    __shared__ short FbH[NSEG * DIM];
    __shared__ short FbL[NSEG * DIM];
    __shared__ short Qh_s[4 * 2 * NSEG * PH];   // hi at 0, lo at +HL; P reuses Q
    __shared__ short Kh_s[4 * 2 * NSEG * PH];
    __shared__ short Vt_s[4 * 2 * NSEG * PH];
    __shared__ float LG[NSEG], SCC[NSEG], SCV[NSEG], POOL[DIM];

    const int tid  = threadIdx.x;
    const int lane = tid & 63;
    const int w    = tid >> 6;
    const int ray  = blockIdx.x;

    // ---- ray geometry (block-uniform) ----
    const float ox = points[ray*6+0], oy = points[ray*6+1], oz = points[ray*6+2];
    float dx = points[ray*6+3] - ox, dy = points[ray*6+4] - oy, dz = points[ray*6+5] - oz;
    const float dn = sqrtf(dx*dx + dy*dy + dz*dz);
    dx /= dn; dy /= dn; dz /= dn;
    const float bq = ox*dx + oy*dy + oz*dz;
    const float cq = ox*ox + oy*oy + oz*oz - 9.0f;
    const float sqv = sqrtf(fmaxf(bq*bq - cq, 0.0f));
    const float t1 = -bq - sqv, t2 = -bq + sqv;
    int n_left = 0;
#pragma unroll
    for (int j = 0; j < NSEG; ++j) {
        float tj = t1 + (float)j * SEGL;
        n_left += (tj < t2) ? 1 : 0;
    }

    // ---- positional encoding -> AbH/AbL (swizzled; cols 72..95 zero for K-pad) ----
    for (int e = tid; e < NSEG * 96; e += 256) {
        int s = e / 96, c = e - (e / 96) * 96;
        float val = 0.f;
        if (c < ENCD) {
            int ep = c / 36, rem = c - ep * 36, coord = rem / 12, u = rem - coord * 12;
            int jj = s + ep;
            float tj = t1 + (float)jj * SEGL;
            float oc = (coord == 0) ? ox : ((coord == 1) ? oy : oz);
            float vc = (coord == 0) ? dx : ((coord == 1) ? dy : dz);
            float pv = (oc + vc * tj) / 3.0f;
            if (s >= n_left) pv = 0.0f;
            int fq = (u < 6) ? u : (u - 6);
            float ang = pv * (3.14159265358979323846f * (float)(1 << fq));
            val = (u < 6) ? __sinf(ang) : __cosf(ang);
        }
        int byte = (s * 256 + c * 2) ^ ((s & 7) << 4);
        short h, l;
        split2(val, h, l);
        *(short*)((char*)AbH + byte) = h;
        *(short*)((char*)AbL + byte) = l;
    }
    __syncthreads();

    // ---- x = enc @ W_up + b_up ----
    {
        f32x4 acc[2][2] = {};
        mfma_gemm3<3>(AbH, AbL, Wf + 393216 + w * 3072, acc, lane);
#pragma unroll
        for (int c = 0; c < 2; ++c) {
            int colg = w * 32 + c * 16 + (lane & 15);
            float bv = b_up[colg];
#pragma unroll
            for (int rt = 0; rt < 2; ++rt)
#pragma unroll
                for (int i = 0; i < 4; ++i) {
                    int row = rt * 16 + ((lane >> 4) << 2) + i;
                    X[row * PXF + colg] = acc[rt][c][i] + bv;
                }
        }
    }
    __syncthreads();

    const float scale = 0.17677669529663687f;  // 1/sqrt(32)
    short* Qh = Qh_s + w * (2 * NSEG * PH);
    short* Kh = Kh_s + w * (2 * NSEG * PH);
    short* Vt = Vt_s + w * (2 * NSEG * PH);

    for (int l = 0; l < 2; ++l) {
        const short* WL = Wf + l * 196608;
        // LN1 -> Ab
        ln_to_Ab(X, ln1_s + l * DIM, ln1_b + l * DIM, AbH, AbL, tid);
        __syncthreads();
        // Q,K,V (wave w = head w's 32 dims)
        {
            f32x4 aq[2][2] = {}, ak[2][2] = {}, av[2][2] = {};
            mfma_gemm3<4>(AbH, AbL, WL + 0 * 16384 + w * 4096, aq, lane);
            mfma_gemm3<4>(AbH, AbL, WL + 1 * 16384 + w * 4096, ak, lane);
            mfma_gemm3<4>(AbH, AbL, WL + 2 * 16384 + w * 4096, av, lane);
#pragma unroll
            for (int c = 0; c < 2; ++c)
#pragma unroll
                for (int rt = 0; rt < 2; ++rt)
#pragma unroll
                    for (int i = 0; i < 4; ++i) {
                        int row = rt * 16 + ((lane >> 4) << 2) + i;
                        int cl  = c * 16 + (lane & 15);
                        short h, lo;
                        split2(aq[rt][c][i], h, lo);
                        Qh[row * PH + cl] = h; Qh[HL + row * PH + cl] = lo;
                        split2(ak[rt][c][i], h, lo);
                        Kh[row * PH + cl] = h; Kh[HL + row * PH + cl] = lo;
                        split2(av[rt][c][i], h, lo);
                        Vt[cl * PH + row] = h; Vt[HL + cl * PH + row] = lo;  // transposed
                    }
        }
        __syncthreads();   // protects Ab before attn-O overwrites it

        // ---- attention (one head per wave, bf16x3) ----
        {
            f32x4 sA[2][2] = {};
            short8 qh[2], ql[2], kh[2], kl[2];
#pragma unroll
            for (int rt = 0; rt < 2; ++rt) {
                int byte = (rt * 16 + (lane & 15)) * (PH * 2) + ((lane >> 4) << 4);
                qh[rt] = *(const short8*)((const char*)Qh + byte);
                ql[rt] = *(const short8*)((const char*)Qh + HL * 2 + byte);
            }
#pragma unroll
            for (int ct = 0; ct < 2; ++ct) {
                int byte = (ct * 16 + (lane & 15)) * (PH * 2) + ((lane >> 4) << 4);
                kh[ct] = *(const short8*)((const char*)Kh + byte);
                kl[ct] = *(const short8*)((const char*)Kh + HL * 2 + byte);
            }
#pragma unroll
            for (int ct = 0; ct < 2; ++ct)
#pragma unroll
                for (int rt = 0; rt < 2; ++rt) {
                    sA[rt][ct] = MFMA(qh[rt], kh[ct], sA[rt][ct]);
                    sA[rt][ct] = MFMA(ql[rt], kh[ct], sA[rt][ct]);
                    sA[rt][ct] = MFMA(qh[rt], kl[ct], sA[rt][ct]);
                }

            // row softmax (row spread over 16 lanes x 2 ctiles) -> P into Qh tiles (hi/lo)
#pragma unroll
            for (int rt = 0; rt < 2; ++rt)
#pragma unroll
                for (int i = 0; i < 4; ++i) {
                    float v0 = sA[rt][0][i] * scale, v1 = sA[rt][1][i] * scale;
                    float mx = fmaxf(v0, v1);
                    mx = fmaxf(mx, __shfl_xor(mx, 1));
                    mx = fmaxf(mx, __shfl_xor(mx, 2));
                    mx = fmaxf(mx, __shfl_xor(mx, 4));
                    mx = fmaxf(mx, __shfl_xor(mx, 8));
                    float e0 = __expf(v0 - mx), e1 = __expf(v1 - mx);
                    float sm = e0 + e1;
                    sm += __shfl_xor(sm, 1);
                    sm += __shfl_xor(sm, 2);
                    sm += __shfl_xor(sm, 4);
                    sm += __shfl_xor(sm, 8);
                    float inv = 1.0f / sm;
                    int row = rt * 16 + ((lane >> 4) << 2) + i;
                    short h, lo;
                    split2(e0 * inv, h, lo);
                    Qh[row * PH + (lane & 15)] = h;
                    Qh[HL + row * PH + (lane & 15)] = lo;
                    split2(e1 * inv, h, lo);
                    Qh[row * PH + 16 + (lane & 15)] = h;
                    Qh[HL + row * PH + 16 + (lane & 15)] = lo;
                }

            // O = P @ V   (same-wave DS ordering: no barrier needed)
            f32x4 oA[2][2] = {};
            short8 ph[2], pl[2], vh[2], vl[2];
#pragma unroll
            for (int rt = 0; rt < 2; ++rt) {
                int byte = (rt * 16 + (lane & 15)) * (PH * 2) + ((lane >> 4) << 4);
                ph[rt] = *(const short8*)((const char*)Qh + byte);
                pl[rt] = *(const short8*)((const char*)Qh + HL * 2 + byte);
            }
#pragma unroll
            for (int ct = 0; ct < 2; ++ct) {
                int byte = (ct * 16 + (lane & 15)) * (PH * 2) + ((lane >> 4) << 4);
                vh[ct] = *(const short8*)((const char*)Vt + byte);
                vl[ct] = *(const short8*)((const char*)Vt + HL * 2 + byte);
            }
#pragma unroll
            for (int ct = 0; ct < 2; ++ct)
#pragma unroll
                for (int rt = 0; rt < 2; ++rt) {
                    oA[rt][ct] = MFMA(ph[rt], vh[ct], oA[rt][ct]);
                    oA[rt][ct] = MFMA(pl[rt], vh[ct], oA[rt][ct]);
                    oA[rt][ct] = MFMA(ph[rt], vl[ct], oA[rt][ct]);
                }

            // O -> Ab (hi/lo swizzled); head w owns cols [32w,32w+32)
#pragma unroll
            for (int rt = 0; rt < 2; ++rt)
#pragma unroll
                for (int ct = 0; ct < 2; ++ct)
#pragma unroll
                    for (int i = 0; i < 4; ++i) {
                        int row  = rt * 16 + ((lane >> 4) << 2) + i;
                        int colg = w * 32 + ct * 16 + (lane & 15);
                        int byte = (row * 256 + colg * 2) ^ ((row & 7) << 4);
                        short h, lo;
                        split2(oA[rt][ct][i], h, lo);
                        *(short*)((char*)AbH + byte) = h;
                        *(short*)((char*)AbL + byte) = lo;
                    }
        }
        __syncthreads();

        // x += O @ Wo
        {
            f32x4 ac[2][2] = {};
            mfma_gemm3<4>(AbH, AbL, WL + 3 * 16384 + w * 4096, ac, lane);
#pragma unroll
            for (int c = 0; c < 2; ++c) {
                int colg = w * 32 + c * 16 + (lane & 15);
#pragma unroll
                for (int rt = 0; rt < 2; ++rt)
#pragma unroll
                    for (int i = 0; i < 4; ++i) {
                        int row = rt * 16 + ((lane >> 4) << 2) + i;
                        X[row * PXF + colg] += ac[rt][c][i];
                    }
            }
        }
        __syncthreads();

        // LN2 -> Ab
        ln_to_Ab(X, ln2_s + l * DIM, ln2_b + l * DIM, AbH, AbL, tid);
        __syncthreads();

        // FFN in 4 chunks of 128 ff-dims
        for (int c4 = 0; c4 < 4; ++c4) {
            {
                f32x4 f1[2][2] = {};
                mfma_gemm3<4>(AbH, AbL, WL + (4 + c4) * 16384 + w * 4096, f1, lane);
#pragma unroll
                for (int c = 0; c < 2; ++c) {
                    int colg = w * 32 + c * 16 + (lane & 15);
                    float bv = b1[l * DFF + c4 * 128 + colg];
#pragma unroll
                    for (int rt = 0; rt < 2; ++rt)
#pragma unroll
                        for (int i = 0; i < 4; ++i) {
                            int row  = rt * 16 + ((lane >> 4) << 2) + i;
                            float v  = fmaxf(f1[rt][c][i] + bv, 0.0f);
                            int byte = (row * 256 + colg * 2) ^ ((row & 7) << 4);
                            short h, lo;
                            split2(v, h, lo);
                            *(short*)((char*)FbH + byte) = h;
                            *(short*)((char*)FbL + byte) = lo;
                        }
                }
            }
            __syncthreads();
            {
                f32x4 f2a[2][2] = {};
                mfma_gemm3<4>(FbH, FbL, WL + (8 + c4) * 16384 + w * 4096, f2a, lane);
#pragma unroll
                for (int c = 0; c < 2; ++c) {
                    int colg = w * 32 + c * 16 + (lane & 15);
                    float bv = (c4 == 0) ? b2[l * DIM + colg] : 0.0f;
#pragma unroll
                    for (int rt = 0; rt < 2; ++rt)
#pragma unroll
                        for (int i = 0; i < 4; ++i) {
                            int row = rt * 16 + ((lane >> 4) << 2) + i;
                            X[row * PXF + colg] += f2a[rt][c][i] + bv;
                        }
                }
            }
            __syncthreads();
        }
    }

    // ---- pooling logits ----
    {
        const int s = tid >> 3, p = tid & 7;
        float acc = 0.f;
        const float* row = X + s * PXF + p * 16;
        const float* wp = w_pool + p * 16;
#pragma unroll
        for (int j = 0; j < 16; ++j) acc = fmaf(row[j], wp[j], acc);
#pragma unroll
        for (int off = 1; off < 8; off <<= 1) acc += __shfl_xor(acc, off);
        if (p == 0) LG[s] = acc;
    }
    __syncthreads();
    if (tid < DIM) {
        float m = -1e30f;
        for (int s = 0; s < NSEG; ++s) m = fmaxf(m, LG[s]);
        float ssum = 0.f;
        for (int s = 0; s < NSEG; ++s) ssum += __expf(LG[s] - m);
        float inv = 1.0f / ssum;
        float acc = 0.f;
        for (int s = 0; s < NSEG; ++s) acc = fmaf(__expf(LG[s] - m), X[s * PXF + tid], acc);
        POOL[tid] = acc * inv;
    }
    {
        const int s = tid >> 3, p = tid & 7;
        float c = 0.f, v = 0.f;
        const float* row = X + s * PXF + p * 16;
#pragma unroll
        for (int j = 0; j < 16; ++j) {
            float x = row[j];
            c = fmaf(x, W_dc[p * 16 + j], c);
            v = fmaf(x, W_dv[p * 16 + j], v);
        }
#pragma unroll
        for (int off = 1; off < 8; off <<= 1) { c += __shfl_xor(c, off); v += __shfl_xor(v, off); }
        if (p == 0) {
            SCC[s] = c + b_dc[0];
            SCV[s] = fminf(fmaxf(v + b_dv[0], 0.0f), 1.0f);
        }
    }
    __syncthreads();
    if (tid < 64) {
        float v = POOL[tid] * W_hit[tid] + POOL[tid + 64] * W_hit[tid + 64];
#pragma unroll
        for (int off = 1; off < 64; off <<= 1) v += __shfl_xor(v, off);
        if (tid == 0) {
            float hv = v + b_hit[0];
            out[ray] = (n_left == 0) ? -100.0f : hv;
        }
    }
    if (tid == 255) {
        float best = -1e30f; int am = 0;
        for (int s = 0; s < NSEG; ++s) {
            if (s < n_left) {
                float cv = SCC[s];
                if (cv > best) { best = cv; am = s; }
            }
        }
        out[NRAYS + ray] = SCV[am] + (float)am * SEGL + t1;
    }
}

extern "C" void kernel_launch(void* const* d_in, const int* in_sizes, int n_in,
                              void* d_out, int out_size, void* d_ws, size_t ws_size,
                              hipStream_t stream) {
    (void)in_sizes; (void)n_in; (void)ws_size; (void)out_size;
    const float* points = (const float*)d_in[0];
    const float* W_up   = (const float*)d_in[1];
    const float* b_up   = (const float*)d_in[2];
    const float* ln1_s  = (const float*)d_in[3];
    const float* ln1_b  = (const float*)d_in[4];
    const float* Wq     = (const float*)d_in[5];
    const float* Wk     = (const float*)d_in[6];
    const float* Wv     = (const float*)d_in[7];
    const float* Wo     = (const float*)d_in[8];
    const float* ln2_s  = (const float*)d_in[9];
    const float* ln2_b  = (const float*)d_in[10];
    const float* W1     = (const float*)d_in[11];
    const float* b1     = (const float*)d_in[12];
    const float* W2     = (const float*)d_in[13];
    const float* b2     = (const float*)d_in[14];
    const float* w_pool = (const float*)d_in[15];
    const float* W_hit  = (const float*)d_in[16];
    const float* b_hit  = (const float*)d_in[17];
    const float* W_dc   = (const float*)d_in[18];
    const float* b_dc   = (const float*)d_in[19];
    const float* W_dv   = (const float*)d_in[20];
    const float* b_dv   = (const float*)d_in[21];
    short* Wf = (short*)d_ws;
    float* out = (float*)d_out;

    hipLaunchKernelGGL(prep_weights, dim3(1584), dim3(256), 0, stream,
                       W_up, Wq, Wk, Wv, Wo, W1, W2, Wf);
    hipLaunchKernelGGL(ray_tf_kernel, dim3(NRAYS), dim3(256), 0, stream,
                       points, b_up, ln1_s, ln1_b, ln2_s, ln2_b, b1, b2, w_pool,
                       W_hit, b_hit, W_dc, b_dc, W_dv, b_dv, Wf, out);
}

// Round 9
// 3095.115 us; speedup vs baseline: 2.6391x; 1.0611x over previous
//
#include <hip/hip_runtime.h>
#include <math.h>

#define NRAYS  16384
#define NSEG   32
#define DIM    128
#define DFF    512
#define ENCD   72
#define PXF    132       // fp32 residual pitch (R3-exact)
#define PH     40        // bf16 per-head pitch (shorts): 80B rows, 16B-aligned
#define HL     (NSEG*PH) // hi->lo short offset inside a head tile
#define SEGL   0.1875f
#define LOOFF  405504    // hi->lo short offset in the weight fragment stream

typedef __attribute__((ext_vector_type(8))) short short8;
typedef __attribute__((ext_vector_type(4))) float f32x4;

__device__ __forceinline__ short f2b(float x) {   // fp32 -> bf16 RNE
    unsigned u = __float_as_uint(x);
    u += 0x7fff + ((u >> 16) & 1);
    return (short)(u >> 16);
}
__device__ __forceinline__ float b2f(short s) {
    return __uint_as_float(((unsigned)(unsigned short)s) << 16);
}
__device__ __forceinline__ void split2(float v, short &h, short &l) {
    h = f2b(v);
    l = f2b(v - b2f(h));
}

// ---------------- weight prep: fp32 -> bf16 hi/lo MFMA B-fragment streams ----------------
__global__ __launch_bounds__(256)
void prep_weights(const float* __restrict__ W_up, const float* __restrict__ Wq,
                  const float* __restrict__ Wk, const float* __restrict__ Wv,
                  const float* __restrict__ Wo, const float* __restrict__ W1,
                  const float* __restrict__ W2, short* __restrict__ out)
{
    int t = blockIdx.x * 256 + threadIdx.x;
    int j    = t & 7;
    int lane = (t >> 3) & 63;
    int krow = ((lane >> 4) << 3) + j;
    int ncol = lane & 15;
    float v;
    if (t < 393216) {
        int f = (t >> 9) & 7;
        int w = (t >> 12) & 3;
        int g = t >> 14;
        int kk = f >> 1, c = f & 1;
        int k = kk * 32 + krow;
        int n = w * 32 + c * 16 + ncol;
        int l = g / 12, gi = g - l * 12;
        if (gi < 4) {
            const float* s4 = (gi == 0) ? Wq : (gi == 1) ? Wk : (gi == 2) ? Wv : Wo;
            v = s4[l * 16384 + k * 128 + n];
        } else if (gi < 8) {
            v = W1[l * 65536 + k * 512 + (gi - 4) * 128 + n];
        } else {
            v = W2[l * 65536 + ((gi - 8) * 128 + k) * 128 + n];
        }
    } else {
        int t2 = t - 393216;         // [0, 12288)
        int w = t2 / 3072;
        int rem = t2 - w * 3072;
        int f = rem >> 9;            // 0..5
        int kk = f >> 1, c = f & 1;
        int k = kk * 32 + krow;
        int n = w * 32 + c * 16 + ncol;
        v = (k < ENCD) ? W_up[k * 128 + n] : 0.0f;
    }
    short h, l2;
    split2(v, h, l2);
    out[t] = h;
    out[t + LOOFF] = l2;
}

// A-operand fragment from swizzled row-major [32][128] bf16 LDS tile
__device__ __forceinline__ short8 lds_afrag(const short* Abuf, int rt, int kk, int lane) {
    int row  = rt * 16 + (lane & 15);
    int byte = row * 256 + kk * 64 + ((lane >> 4) << 4);
    byte ^= (row & 7) << 4;
    return *(const short8*)((const char*)Abuf + byte);
}

#define MFMA(a,b,c) __builtin_amdgcn_mfma_f32_16x16x32_bf16((a),(b),(c),0,0,0)

// OUT(32x128) += A(32xK, hi/lo LDS tiles) @ B(hi/lo frag streams); bf16x3 emulation
template<int NK>
__device__ __forceinline__ void mfma_gemm3(const short* AbH, const short* AbL,
                                           const short* BwH, f32x4 acc[2][2], int lane) {
    const short* BwL = BwH + LOOFF;
#pragma unroll
    for (int kk = 0; kk < NK; ++kk) {
        short8 ah0 = lds_afrag(AbH, 0, kk, lane);
        short8 ah1 = lds_afrag(AbH, 1, kk, lane);
        short8 al0 = lds_afrag(AbL, 0, kk, lane);
        short8 al1 = lds_afrag(AbL, 1, kk, lane);
        short8 bh0 = *(const short8*)(BwH + ((kk * 2 + 0) * 64 + lane) * 8);
        short8 bh1 = *(const short8*)(BwH + ((kk * 2 + 1) * 64 + lane) * 8);
        short8 bl0 = *(const short8*)(BwL + ((kk * 2 + 0) * 64 + lane) * 8);
        short8 bl1 = *(const short8*)(BwL + ((kk * 2 + 1) * 64 + lane) * 8);
        acc[0][0] = MFMA(ah0, bh0, acc[0][0]);
        acc[1][0] = MFMA(ah1, bh0, acc[1][0]);
        acc[0][1] = MFMA(ah0, bh1, acc[0][1]);
        acc[1][1] = MFMA(ah1, bh1, acc[1][1]);
        acc[0][0] = MFMA(al0, bh0, acc[0][0]);
        acc[1][0] = MFMA(al1, bh0, acc[1][0]);
        acc[0][1] = MFMA(al0, bh1, acc[0][1]);
        acc[1][1] = MFMA(al1, bh1, acc[1][1]);
        acc[0][0] = MFMA(ah0, bl0, acc[0][0]);
        acc[1][0] = MFMA(ah1, bl0, acc[1][0]);
        acc[0][1] = MFMA(ah0, bl1, acc[0][1]);
        acc[1][1] = MFMA(ah1, bl1, acc[1][1]);
    }
}

// LayerNorm from fp32 X -> swizzled hi/lo bf16 A-tiles (sync-free: 8-thread shfl reduce)
__device__ __forceinline__ void ln_to_Ab(const float* Xs, const float* sc, const float* bi,
                                         short* AbH, short* AbL, int tid) {
    const int s = tid >> 3, p = tid & 7;
    const float* row = Xs + s * PXF + p * 16;
    float sum = 0.f, sq = 0.f;
#pragma unroll
    for (int j = 0; j < 16; ++j) { float v = row[j]; sum += v; sq = fmaf(v, v, sq); }
#pragma unroll
    for (int off = 1; off < 8; off <<= 1) { sum += __shfl_xor(sum, off); sq += __shfl_xor(sq, off); }
    float mu = sum * 0.0078125f;
    float rs = rsqrtf(sq * 0.0078125f - mu * mu + 1e-5f);
    short8 o0h, o1h, o0l, o1l;
#pragma unroll
    for (int j = 0; j < 8; ++j) {
        float v0 = (row[j]     - mu) * rs * sc[p * 16 + j]     + bi[p * 16 + j];
        float v1 = (row[j + 8] - mu) * rs * sc[p * 16 + 8 + j] + bi[p * 16 + 8 + j];
        short h, l;
        split2(v0, h, l); o0h[j] = h; o0l[j] = l;
        split2(v1, h, l); o1h[j] = h; o1l[j] = l;
    }
    int base = s * 256 + p * 32, swz = (s & 7) << 4;
    *(short8*)((char*)AbH + ((base)      ^ swz)) = o0h;
    *(short8*)((char*)AbH + ((base + 16) ^ swz)) = o1h;
    *(short8*)((char*)AbL + ((base)      ^ swz)) = o0l;
    *(short8*)((char*)AbL + ((base + 16) ^ swz)) = o1l;
}

__global__ __launch_bounds__(256)
void ray_tf_kernel(const float* __restrict__ points,
                   const float* __restrict__ b_up,
                   const float* __restrict__ ln1_s, const float* __restrict__ ln1_b,
                   const float* __restrict__ ln2_s, const float* __restrict__ ln2_b,
                   const float* __restrict__ b1, const float* __restrict__ b2,
                   const float* __restrict__ w_pool,
                   const float* __restrict__ W_hit, const float* __restrict__ b_hit,
                   const float* __restrict__ W_dc, const float* __restrict__ b_dc,
                   const float* __restrict__ W_dv, const float* __restrict__ b_dv,
                   const short* __restrict__ Wf,
                   float* __restrict__ out)
{
    __shared__ float X[NSEG * PXF];
    __shared__ short AbH[NSEG * DIM];
    __shared__ short AbL[NSEG * DIM];
    __shared__ short Qh_s[4 * 2 * NSEG * PH];   // QP tiles: hi at 0, lo at +HL; P reuses Q (R3 construct)
    __shared__ short Kh_s[4 * 2 * NSEG * PH];   // K tiles in attention; aliased by Fb in FFN (phase-disjoint)
    __shared__ float LG[NSEG], SCC[NSEG], SCV[NSEG], POOL[DIM];

    const int tid  = threadIdx.x;
    const int lane = tid & 63;
    const int w    = tid >> 6;
    const int ray  = blockIdx.x;

    short* Qh  = Qh_s + w * (2 * NSEG * PH);
    short* Kh  = Kh_s + w * (2 * NSEG * PH);
    short* FbH = Kh_s;                 // FFN scratch aliases K tiles only (dead after QK^T,
    short* FbL = Kh_s + 4096;          // >=2 barriers separate the phases in both directions)

    // ---- ray geometry (block-uniform) ----
    const float ox = points[ray*6+0], oy = points[ray*6+1], oz = points[ray*6+2];
    float dx = points[ray*6+3] - ox, dy = points[ray*6+4] - oy, dz = points[ray*6+5] - oz;
    const float dn = sqrtf(dx*dx + dy*dy + dz*dz);
    dx /= dn; dy /= dn; dz /= dn;
    const float bq = ox*dx + oy*dy + oz*dz;
    const float cq = ox*ox + oy*oy + oz*oz - 9.0f;
    const float sqv = sqrtf(fmaxf(bq*bq - cq, 0.0f));
    const float t1 = -bq - sqv, t2 = -bq + sqv;
    int n_left = 0;
#pragma unroll
    for (int j = 0; j < NSEG; ++j) {
        float tj = t1 + (float)j * SEGL;
        n_left += (tj < t2) ? 1 : 0;
    }

    // ---- positional encoding -> AbH/AbL (swizzled; cols 72..95 zero for K-pad) ----
    for (int e = tid; e < NSEG * 96; e += 256) {
        int s = e / 96, c = e - (e / 96) * 96;
        float val = 0.f;
        if (c < ENCD) {
            int ep = c / 36, rem = c - ep * 36, coord = rem / 12, u = rem - coord * 12;
            int jj = s + ep;
            float tj = t1 + (float)jj * SEGL;
            float oc = (coord == 0) ? ox : ((coord == 1) ? oy : oz);
            float vc = (coord == 0) ? dx : ((coord == 1) ? dy : dz);
            float pv = (oc + vc * tj) / 3.0f;
            if (s >= n_left) pv = 0.0f;
            int fq = (u < 6) ? u : (u - 6);
            float ang = pv * (3.14159265358979323846f * (float)(1 << fq));
            val = (u < 6) ? __sinf(ang) : __cosf(ang);
        }
        int byte = (s * 256 + c * 2) ^ ((s & 7) << 4);
        short h, l;
        split2(val, h, l);
        *(short*)((char*)AbH + byte) = h;
        *(short*)((char*)AbL + byte) = l;
    }
    __syncthreads();

    // ---- x = enc @ W_up + b_up ----
    {
        f32x4 acc[2][2] = {};
        mfma_gemm3<3>(AbH, AbL, Wf + 393216 + w * 3072, acc, lane);
#pragma unroll
        for (int c = 0; c < 2; ++c) {
            int colg = w * 32 + c * 16 + (lane & 15);
            float bv = b_up[colg];
#pragma unroll
            for (int rt = 0; rt < 2; ++rt)
#pragma unroll
                for (int i = 0; i < 4; ++i) {
                    int row = rt * 16 + ((lane >> 4) << 2) + i;
                    X[row * PXF + colg] = acc[rt][c][i] + bv;
                }
        }
    }
    __syncthreads();

    const float scale = 0.17677669529663687f;  // 1/sqrt(32)

    for (int l = 0; l < 2; ++l) {
        const short* WL = Wf + l * 196608;
        // LN1 -> Ab
        ln_to_Ab(X, ln1_s + l * DIM, ln1_b + l * DIM, AbH, AbL, tid);
        __syncthreads();

        // Q,K,V GEMMs, R3's exact sequential stream (wave w = head w's 32 dims)
        f32x4 aq[2][2] = {}, ak[2][2] = {}, av[2][2] = {};
        mfma_gemm3<4>(AbH, AbL, WL + 0 * 16384 + w * 4096, aq, lane);
        mfma_gemm3<4>(AbH, AbL, WL + 1 * 16384 + w * 4096, ak, lane);
        mfma_gemm3<4>(AbH, AbL, WL + 2 * 16384 + w * 4096, av, lane);
        // write Q, K hi/lo tiles (V stays in registers; never enters LDS)
#pragma unroll
        for (int c = 0; c < 2; ++c)
#pragma unroll
            for (int rt = 0; rt < 2; ++rt)
#pragma unroll
                for (int i = 0; i < 4; ++i) {
                    int row = rt * 16 + ((lane >> 4) << 2) + i;
                    int cl  = c * 16 + (lane & 15);
                    short h, lo;
                    split2(aq[rt][c][i], h, lo);
                    Qh[row * PH + cl] = h; Qh[HL + row * PH + cl] = lo;
                    split2(ak[rt][c][i], h, lo);
                    Kh[row * PH + cl] = h; Kh[HL + row * PH + cl] = lo;
                }
        __syncthreads();   // all waves done reading Ab (QKV) before attn-O overwrites it

        // ---- attention (one head per wave, bf16x3; R3 op order) ----
        {
            f32x4 sA[2][2] = {};
            short8 qh[2], ql[2], kh[2], kl[2];
#pragma unroll
            for (int rt = 0; rt < 2; ++rt) {
                int byte = (rt * 16 + (lane & 15)) * (PH * 2) + ((lane >> 4) << 4);
                qh[rt] = *(const short8*)((const char*)Qh + byte);
                ql[rt] = *(const short8*)((const char*)Qh + HL * 2 + byte);
            }
#pragma unroll
            for (int ct = 0; ct < 2; ++ct) {
                int byte = (ct * 16 + (lane & 15)) * (PH * 2) + ((lane >> 4) << 4);
                kh[ct] = *(const short8*)((const char*)Kh + byte);
                kl[ct] = *(const short8*)((const char*)Kh + HL * 2 + byte);
            }
#pragma unroll
            for (int ct = 0; ct < 2; ++ct)
#pragma unroll
                for (int rt = 0; rt < 2; ++rt) {
                    sA[rt][ct] = MFMA(qh[rt], kh[ct], sA[rt][ct]);
                    sA[rt][ct] = MFMA(ql[rt], kh[ct], sA[rt][ct]);
                    sA[rt][ct] = MFMA(qh[rt], kl[ct], sA[rt][ct]);
                }

            // V: register transpose acc-layout -> PV B-fragment layout.
            // Shuffle BOTH rt candidates; select by DESTINATION half. Value-exact vs
            // the R3 LDS round-trip (shuffle exact, split2 after).
            short8 vbh[2], vbl[2];
#pragma unroll
            for (int ct = 0; ct < 2; ++ct)
#pragma unroll
                for (int j = 0; j < 8; ++j) {
                    int srcl = ((((lane >> 4) & 1) * 2 + (j >> 2)) << 4) | (lane & 15);
                    float v0 = __shfl(av[0][ct][j & 3], srcl);
                    float v1 = __shfl(av[1][ct][j & 3], srcl);
                    float vv = (lane < 32) ? v0 : v1;
                    short h, lo;
                    split2(vv, h, lo);
                    vbh[ct][j] = h; vbl[ct][j] = lo;
                }

            // row softmax -> P into QP tile (hi/lo); in-wave DS ordering (R3 construct)
#pragma unroll
            for (int rt = 0; rt < 2; ++rt)
#pragma unroll
                for (int i = 0; i < 4; ++i) {
                    float v0 = sA[rt][0][i] * scale, v1 = sA[rt][1][i] * scale;
                    float mx = fmaxf(v0, v1);
                    mx = fmaxf(mx, __shfl_xor(mx, 1));
                    mx = fmaxf(mx, __shfl_xor(mx, 2));
                    mx = fmaxf(mx, __shfl_xor(mx, 4));
                    mx = fmaxf(mx, __shfl_xor(mx, 8));
                    float e0 = __expf(v0 - mx), e1 = __expf(v1 - mx);
                    float sm = e0 + e1;
                    sm += __shfl_xor(sm, 1);
                    sm += __shfl_xor(sm, 2);
                    sm += __shfl_xor(sm, 4);
                    sm += __shfl_xor(sm, 8);
                    float inv = 1.0f / sm;
                    int row = rt * 16 + ((lane >> 4) << 2) + i;
                    short h, lo;
                    split2(e0 * inv, h, lo);
                    Qh[row * PH + (lane & 15)] = h;
                    Qh[HL + row * PH + (lane & 15)] = lo;
                    split2(e1 * inv, h, lo);
                    Qh[row * PH + 16 + (lane & 15)] = h;
                    Qh[HL + row * PH + 16 + (lane & 15)] = lo;
                }

            // O = P @ V  (P from QP tile, V from registers)
            f32x4 oA[2][2] = {};
            short8 ph[2], pl[2];
#pragma unroll
            for (int rt = 0; rt < 2; ++rt) {
                int byte = (rt * 16 + (lane & 15)) * (PH * 2) + ((lane >> 4) << 4);
                ph[rt] = *(const short8*)((const char*)Qh + byte);
                pl[rt] = *(const short8*)((const char*)Qh + HL * 2 + byte);
            }
#pragma unroll
            for (int ct = 0; ct < 2; ++ct)
#pragma unroll
                for (int rt = 0; rt < 2; ++rt) {
                    oA[rt][ct] = MFMA(ph[rt], vbh[ct], oA[rt][ct]);
                    oA[rt][ct] = MFMA(pl[rt], vbh[ct], oA[rt][ct]);
                    oA[rt][ct] = MFMA(ph[rt], vbl[ct], oA[rt][ct]);
                }

            // O -> Ab (hi/lo swizzled); head w owns cols [32w,32w+32)
#pragma unroll
            for (int rt = 0; rt < 2; ++rt)
#pragma unroll
                for (int ct = 0; ct < 2; ++ct)
#pragma unroll
                    for (int i = 0; i < 4; ++i) {
                        int row  = rt * 16 + ((lane >> 4) << 2) + i;
                        int colg = w * 32 + ct * 16 + (lane & 15);
                        int byte = (row * 256 + colg * 2) ^ ((row & 7) << 4);
                        short h, lo;
                        split2(oA[rt][ct][i], h, lo);
                        *(short*)((char*)AbH + byte) = h;
                        *(short*)((char*)AbL + byte) = lo;
                    }
        }
        __syncthreads();

        // x += O @ Wo
        {
            f32x4 ac[2][2] = {};
            mfma_gemm3<4>(AbH, AbL, WL + 3 * 16384 + w * 4096, ac, lane);
#pragma unroll
            for (int c = 0; c < 2; ++c) {
                int colg = w * 32 + c * 16 + (lane & 15);
#pragma unroll
                for (int rt = 0; rt < 2; ++rt)
#pragma unroll
                    for (int i = 0; i < 4; ++i) {
                        int row = rt * 16 + ((lane >> 4) << 2) + i;
                        X[row * PXF + colg] += ac[rt][c][i];
                    }
            }
        }
        __syncthreads();

        // LN2 -> Ab
        ln_to_Ab(X, ln2_s + l * DIM, ln2_b + l * DIM, AbH, AbL, tid);
        __syncthreads();

        // FFN in 4 chunks of 128 ff-dims (Fb aliases K tiles; phases barrier-separated)
        for (int c4 = 0; c4 < 4; ++c4) {
            {
                f32x4 f1[2][2] = {};
                mfma_gemm3<4>(AbH, AbL, WL + (4 + c4) * 16384 + w * 4096, f1, lane);
#pragma unroll
                for (int c = 0; c < 2; ++c) {
                    int colg = w * 32 + c * 16 + (lane & 15);
                    float bv = b1[l * DFF + c4 * 128 + colg];
#pragma unroll
                    for (int rt = 0; rt < 2; ++rt)
#pragma unroll
                        for (int i = 0; i < 4; ++i) {
                            int row  = rt * 16 + ((lane >> 4) << 2) + i;
                            float v  = fmaxf(f1[rt][c][i] + bv, 0.0f);
                            int byte = (row * 256 + colg * 2) ^ ((row & 7) << 4);
                            short h, lo;
                            split2(v, h, lo);
                            *(short*)((char*)FbH + byte) = h;
                            *(short*)((char*)FbL + byte) = lo;
                        }
                }
            }
            __syncthreads();
            {
                f32x4 f2a[2][2] = {};
                mfma_gemm3<4>(FbH, FbL, WL + (8 + c4) * 16384 + w * 4096, f2a, lane);
#pragma unroll
                for (int c = 0; c < 2; ++c) {
                    int colg = w * 32 + c * 16 + (lane & 15);
                    float bv = (c4 == 0) ? b2[l * DIM + colg] : 0.0f;
#pragma unroll
                    for (int rt = 0; rt < 2; ++rt)
#pragma unroll
                        for (int i = 0; i < 4; ++i) {
                            int row = rt * 16 + ((lane >> 4) << 2) + i;
                            X[row * PXF + colg] += f2a[rt][c][i] + bv;
                        }
                }
            }
            __syncthreads();
        }
    }

    // ---- pooling logits ----
    {
        const int s = tid >> 3, p = tid & 7;
        float acc = 0.f;
        const float* row = X + s * PXF + p * 16;
        const float* wp = w_pool + p * 16;
#pragma unroll
        for (int j = 0; j < 16; ++j) acc = fmaf(row[j], wp[j], acc);
#pragma unroll
        for (int off = 1; off < 8; off <<= 1) acc += __shfl_xor(acc, off);
        if (p == 0) LG[s] = acc;
    }
    __syncthreads();
    if (tid < DIM) {
        float m = -1e30f;
        for (int s = 0; s < NSEG; ++s) m = fmaxf(m, LG[s]);
        float ssum = 0.f;
        for (int s = 0; s < NSEG; ++s) ssum += __expf(LG[s] - m);
        float inv = 1.0f / ssum;
        float acc = 0.f;
        for (int s = 0; s < NSEG; ++s) acc = fmaf(__expf(LG[s] - m), X[s * PXF + tid], acc);
        POOL[tid] = acc * inv;
    }
    {
        const int s = tid >> 3, p = tid & 7;
        float c = 0.f, v = 0.f;
        const float* row = X + s * PXF + p * 16;
#pragma unroll
        for (int j = 0; j < 16; ++j) {
            float x = row[j];
            c = fmaf(x, W_dc[p * 16 + j], c);
            v = fmaf(x, W_dv[p * 16 + j], v);
        }
#pragma unroll
        for (int off = 1; off < 8; off <<= 1) { c += __shfl_xor(c, off); v += __shfl_xor(v, off); }
        if (p == 0) {
            SCC[s] = c + b_dc[0];
            SCV[s] = fminf(fmaxf(v + b_dv[0], 0.0f), 1.0f);
        }
    }
    __syncthreads();
    if (tid < 64) {
        float v = POOL[tid] * W_hit[tid] + POOL[tid + 64] * W_hit[tid + 64];
#pragma unroll
        for (int off = 1; off < 64; off <<= 1) v += __shfl_xor(v, off);
        if (tid == 0) {
            float hv = v + b_hit[0];
            out[ray] = (n_left == 0) ? -100.0f : hv;
        }
    }
    if (tid == 255) {
        float best = -1e30f; int am = 0;
        for (int s = 0; s < NSEG; ++s) {
            if (s < n_left) {
                float cv = SCC[s];
                if (cv > best) { best = cv; am = s; }
            }
        }
        out[NRAYS + ray] = SCV[am] + (float)am * SEGL + t1;
    }
}

extern "C" void kernel_launch(void* const* d_in, const int* in_sizes, int n_in,
                              void* d_out, int out_size, void* d_ws, size_t ws_size,
                              hipStream_t stream) {
    (void)in_sizes; (void)n_in; (void)ws_size; (void)out_size;
    const float* points = (const float*)d_in[0];
    const float* W_up   = (const float*)d_in[1];
    const float* b_up   = (const float*)d_in[2];
    const float* ln1_s  = (const float*)d_in[3];
    const float* ln1_b  = (const float*)d_in[4];
    const float* Wq     = (const float*)d_in[5];
    const float* Wk     = (const float*)d_in[6];
    const float* Wv     = (const float*)d_in[7];
    const float* Wo     = (const float*)d_in[8];
    const float* ln2_s  = (const float*)d_in[9];
    const float* ln2_b  = (const float*)d_in[10];
    const float* W1     = (const float*)d_in[11];
    const float* b1     = (const float*)d_in[12];
    const float* W2     = (const float*)d_in[13];
    const float* b2     = (const float*)d_in[14];
    const float* w_pool = (const float*)d_in[15];
    const float* W_hit  = (const float*)d_in[16];
    const float* b_hit  = (const float*)d_in[17];
    const float* W_dc   = (const float*)d_in[18];
    const float* b_dc   = (const float*)d_in[19];
    const float* W_dv   = (const float*)d_in[20];
    const float* b_dv   = (const float*)d_in[21];
    short* Wf = (short*)d_ws;
    float* out = (float*)d_out;

    hipLaunchKernelGGL(prep_weights, dim3(1584), dim3(256), 0, stream,
                       W_up, Wq, Wk, Wv, Wo, W1, W2, Wf);
    hipLaunchKernelGGL(ray_tf_kernel, dim3(NRAYS), dim3(256), 0, stream,
                       points, b_up, ln1_s, ln1_b, ln2_s, ln2_b, b1, b2, w_pool,
                       W_hit, b_hit, W_dc, b_dc, W_dv, b_dv, Wf, out);
}

// Round 11
// 2060.677 us; speedup vs baseline: 3.9639x; 1.5020x over previous
//
#include <hip/hip_runtime.h>
#include <math.h>

#define NRAYS  16384
#define NSEG   32
#define DIM    128
#define DFF    512
#define ENCD   72
#define PXF    132       // fp32 residual pitch (R3-exact)
#define PH     40        // bf16 per-head pitch (shorts): 80B rows, 16B-aligned
#define HL     (NSEG*PH) // hi->lo short offset inside a head tile
#define SEGL   0.1875f
#define LOOFF  405504    // hi->lo short offset in the weight fragment stream

typedef __attribute__((ext_vector_type(8))) short short8;
typedef __attribute__((ext_vector_type(4))) float f32x4;

__device__ __forceinline__ short f2b(float x) {   // fp32 -> bf16 RNE
    unsigned u = __float_as_uint(x);
    u += 0x7fff + ((u >> 16) & 1);
    return (short)(u >> 16);
}
__device__ __forceinline__ float b2f(short s) {
    return __uint_as_float(((unsigned)(unsigned short)s) << 16);
}
__device__ __forceinline__ void split2(float v, short &h, short &l) {
    h = f2b(v);
    l = f2b(v - b2f(h));
}

// ---------------- weight prep: fp32 -> bf16 hi/lo MFMA B-fragment streams ----------------
__global__ __launch_bounds__(256)
void prep_weights(const float* __restrict__ W_up, const float* __restrict__ Wq,
                  const float* __restrict__ Wk, const float* __restrict__ Wv,
                  const float* __restrict__ Wo, const float* __restrict__ W1,
                  const float* __restrict__ W2, short* __restrict__ out)
{
    int t = blockIdx.x * 256 + threadIdx.x;
    int j    = t & 7;
    int lane = (t >> 3) & 63;
    int krow = ((lane >> 4) << 3) + j;
    int ncol = lane & 15;
    float v;
    if (t < 393216) {
        int f = (t >> 9) & 7;
        int w = (t >> 12) & 3;
        int g = t >> 14;
        int kk = f >> 1, c = f & 1;
        int k = kk * 32 + krow;
        int n = w * 32 + c * 16 + ncol;
        int l = g / 12, gi = g - l * 12;
        if (gi < 4) {
            const float* s4 = (gi == 0) ? Wq : (gi == 1) ? Wk : (gi == 2) ? Wv : Wo;
            v = s4[l * 16384 + k * 128 + n];
        } else if (gi < 8) {
            v = W1[l * 65536 + k * 512 + (gi - 4) * 128 + n];
        } else {
            v = W2[l * 65536 + ((gi - 8) * 128 + k) * 128 + n];
        }
    } else {
        int t2 = t - 393216;         // [0, 12288)
        int w = t2 / 3072;
        int rem = t2 - w * 3072;
        int f = rem >> 9;            // 0..5
        int kk = f >> 1, c = f & 1;
        int k = kk * 32 + krow;
        int n = w * 32 + c * 16 + ncol;
        v = (k < ENCD) ? W_up[k * 128 + n] : 0.0f;
    }
    short h, l2;
    split2(v, h, l2);
    out[t] = h;
    out[t + LOOFF] = l2;
}

// A-operand fragment from swizzled row-major [32][128] bf16 LDS tile
__device__ __forceinline__ short8 lds_afrag(const short* Abuf, int rt, int kk, int lane) {
    int row  = rt * 16 + (lane & 15);
    int byte = row * 256 + kk * 64 + ((lane >> 4) << 4);
    byte ^= (row & 7) << 4;
    return *(const short8*)((const char*)Abuf + byte);
}

#define MFMA(a,b,c) __builtin_amdgcn_mfma_f32_16x16x32_bf16((a),(b),(c),0,0,0)

// OUT(32x128) += A(32xK, hi/lo LDS tiles) @ B(hi/lo frag streams); bf16x3 emulation
template<int NK>
__device__ __forceinline__ void mfma_gemm3(const short* AbH, const short* AbL,
                                           const short* BwH, f32x4 acc[2][2], int lane) {
    const short* BwL = BwH + LOOFF;
#pragma unroll
    for (int kk = 0; kk < NK; ++kk) {
        short8 ah0 = lds_afrag(AbH, 0, kk, lane);
        short8 ah1 = lds_afrag(AbH, 1, kk, lane);
        short8 al0 = lds_afrag(AbL, 0, kk, lane);
        short8 al1 = lds_afrag(AbL, 1, kk, lane);
        short8 bh0 = *(const short8*)(BwH + ((kk * 2 + 0) * 64 + lane) * 8);
        short8 bh1 = *(const short8*)(BwH + ((kk * 2 + 1) * 64 + lane) * 8);
        short8 bl0 = *(const short8*)(BwL + ((kk * 2 + 0) * 64 + lane) * 8);
        short8 bl1 = *(const short8*)(BwL + ((kk * 2 + 1) * 64 + lane) * 8);
        acc[0][0] = MFMA(ah0, bh0, acc[0][0]);
        acc[1][0] = MFMA(ah1, bh0, acc[1][0]);
        acc[0][1] = MFMA(ah0, bh1, acc[0][1]);
        acc[1][1] = MFMA(ah1, bh1, acc[1][1]);
        acc[0][0] = MFMA(al0, bh0, acc[0][0]);
        acc[1][0] = MFMA(al1, bh0, acc[1][0]);
        acc[0][1] = MFMA(al0, bh1, acc[0][1]);
        acc[1][1] = MFMA(al1, bh1, acc[1][1]);
        acc[0][0] = MFMA(ah0, bl0, acc[0][0]);
        acc[1][0] = MFMA(ah1, bl0, acc[1][0]);
        acc[0][1] = MFMA(ah0, bl1, acc[0][1]);
        acc[1][1] = MFMA(ah1, bl1, acc[1][1]);
    }
}

// LayerNorm from fp32 X -> swizzled hi/lo bf16 A-tiles (sync-free: 8-thread shfl reduce)
__device__ __forceinline__ void ln_to_Ab(const float* Xs, const float* sc, const float* bi,
                                         short* AbH, short* AbL, int t) {
    const int s = t >> 3, p = t & 7;
    const float* row = Xs + s * PXF + p * 16;
    float sum = 0.f, sq = 0.f;
#pragma unroll
    for (int j = 0; j < 16; ++j) { float v = row[j]; sum += v; sq = fmaf(v, v, sq); }
#pragma unroll
    for (int off = 1; off < 8; off <<= 1) { sum += __shfl_xor(sum, off); sq += __shfl_xor(sq, off); }
    float mu = sum * 0.0078125f;
    float rs = rsqrtf(sq * 0.0078125f - mu * mu + 1e-5f);
    short8 o0h, o1h, o0l, o1l;
#pragma unroll
    for (int j = 0; j < 8; ++j) {
        float v0 = (row[j]     - mu) * rs * sc[p * 16 + j]     + bi[p * 16 + j];
        float v1 = (row[j + 8] - mu) * rs * sc[p * 16 + 8 + j] + bi[p * 16 + 8 + j];
        short h, l;
        split2(v0, h, l); o0h[j] = h; o0l[j] = l;
        split2(v1, h, l); o1h[j] = h; o1l[j] = l;
    }
    int base = s * 256 + p * 32, swz = (s & 7) << 4;
    *(short8*)((char*)AbH + ((base)      ^ swz)) = o0h;
    *(short8*)((char*)AbH + ((base + 16) ^ swz)) = o1h;
    *(short8*)((char*)AbL + ((base)      ^ swz)) = o0l;
    *(short8*)((char*)AbL + ((base + 16) ^ swz)) = o1l;
}

// 2 rays per 512-thread block: sub-block 0 = threads 0..255 (ray 2b), sub-block 1 =
// threads 256..511 (ray 2b+1). Every LDS buffer is fully private per sub-block; all
// per-ray math/addressing byte-identical to the passing R9 kernel. Barriers sync both
// rays (superset of required syncs). 8 waves/CU resident (was 4).
__global__ __launch_bounds__(512)
void ray_tf_kernel(const float* __restrict__ points,
                   const float* __restrict__ b_up,
                   const float* __restrict__ ln1_s, const float* __restrict__ ln1_b,
                   const float* __restrict__ ln2_s, const float* __restrict__ ln2_b,
                   const float* __restrict__ b1, const float* __restrict__ b2,
                   const float* __restrict__ w_pool,
                   const float* __restrict__ W_hit, const float* __restrict__ b_hit,
                   const float* __restrict__ W_dc, const float* __restrict__ b_dc,
                   const float* __restrict__ W_dv, const float* __restrict__ b_dv,
                   const short* __restrict__ Wf,
                   float* __restrict__ out)
{
    __shared__ float Xs2[2][NSEG * PXF];
    __shared__ short AbH2[2][NSEG * DIM];
    __shared__ short AbL2[2][NSEG * DIM];
    __shared__ short Qh2[2][4 * 2 * NSEG * PH];   // QP tiles: hi at 0, lo at +HL; P reuses Q
    __shared__ short Kh2[2][4 * 2 * NSEG * PH];   // K tiles; aliased by Fb in FFN (phase-disjoint)
    __shared__ float LG2[2][NSEG], SCC2[2][NSEG], SCV2[2][NSEG], POOL2[2][DIM];

    const int sub  = threadIdx.x >> 8;
    const int t    = threadIdx.x & 255;
    const int lane = t & 63;
    const int w    = t >> 6;
    const int ray  = blockIdx.x * 2 + sub;

    float* X    = Xs2[sub];
    short* AbH  = AbH2[sub];
    short* AbL  = AbL2[sub];
    short* Qh   = Qh2[sub] + w * (2 * NSEG * PH);
    short* Kh   = Kh2[sub] + w * (2 * NSEG * PH);
    short* FbH  = Kh2[sub];            // FFN scratch aliases K tiles (dead after QK^T,
    short* FbL  = Kh2[sub] + 4096;     // >=2 barriers separate the phases both ways)
    float* LG   = LG2[sub];
    float* SCC  = SCC2[sub];
    float* SCV  = SCV2[sub];
    float* POOL = POOL2[sub];

    // ---- ray geometry (sub-block-uniform) ----
    const float ox = points[ray*6+0], oy = points[ray*6+1], oz = points[ray*6+2];
    float dx = points[ray*6+3] - ox, dy = points[ray*6+4] - oy, dz = points[ray*6+5] - oz;
    const float dn = sqrtf(dx*dx + dy*dy + dz*dz);
    dx /= dn; dy /= dn; dz /= dn;
    const float bq = ox*dx + oy*dy + oz*dz;
    const float cq = ox*ox + oy*oy + oz*oz - 9.0f;
    const float sqv = sqrtf(fmaxf(bq*bq - cq, 0.0f));
    const float t1 = -bq - sqv, t2 = -bq + sqv;
    int n_left = 0;
#pragma unroll
    for (int j = 0; j < NSEG; ++j) {
        float tj = t1 + (float)j * SEGL;
        n_left += (tj < t2) ? 1 : 0;
    }

    // ---- positional encoding -> AbH/AbL (swizzled; cols 72..95 zero for K-pad) ----
    for (int e = t; e < NSEG * 96; e += 256) {
        int s = e / 96, c = e - (e / 96) * 96;
        float val = 0.f;
        if (c < ENCD) {
            int ep = c / 36, rem = c - ep * 36, coord = rem / 12, u = rem - coord * 12;
            int jj = s + ep;
            float tj = t1 + (float)jj * SEGL;
            float oc = (coord == 0) ? ox : ((coord == 1) ? oy : oz);
            float vc = (coord == 0) ? dx : ((coord == 1) ? dy : dz);
            float pv = (oc + vc * tj) / 3.0f;
            if (s >= n_left) pv = 0.0f;
            int fq = (u < 6) ? u : (u - 6);
            float ang = pv * (3.14159265358979323846f * (float)(1 << fq));
            val = (u < 6) ? __sinf(ang) : __cosf(ang);
        }
        int byte = (s * 256 + c * 2) ^ ((s & 7) << 4);
        short h, l;
        split2(val, h, l);
        *(short*)((char*)AbH + byte) = h;
        *(short*)((char*)AbL + byte) = l;
    }
    __syncthreads();

    // ---- x = enc @ W_up + b_up ----
    {
        f32x4 acc[2][2] = {};
        mfma_gemm3<3>(AbH, AbL, Wf + 393216 + w * 3072, acc, lane);
#pragma unroll
        for (int c = 0; c < 2; ++c) {
            int colg = w * 32 + c * 16 + (lane & 15);
            float bv = b_up[colg];
#pragma unroll
            for (int rt = 0; rt < 2; ++rt)
#pragma unroll
                for (int i = 0; i < 4; ++i) {
                    int row = rt * 16 + ((lane >> 4) << 2) + i;
                    X[row * PXF + colg] = acc[rt][c][i] + bv;
                }
        }
    }
    __syncthreads();

    const float scale = 0.17677669529663687f;  // 1/sqrt(32)

    for (int l = 0; l < 2; ++l) {
        const short* WL = Wf + l * 196608;
        // LN1 -> Ab
        ln_to_Ab(X, ln1_s + l * DIM, ln1_b + l * DIM, AbH, AbL, t);
        __syncthreads();

        // Q,K,V GEMMs, R3's exact sequential stream (wave w = head w's 32 dims)
        f32x4 aq[2][2] = {}, ak[2][2] = {}, av[2][2] = {};
        mfma_gemm3<4>(AbH, AbL, WL + 0 * 16384 + w * 4096, aq, lane);
        mfma_gemm3<4>(AbH, AbL, WL + 1 * 16384 + w * 4096, ak, lane);
        mfma_gemm3<4>(AbH, AbL, WL + 2 * 16384 + w * 4096, av, lane);
        // write Q, K hi/lo tiles (V stays in registers; never enters LDS)
#pragma unroll
        for (int c = 0; c < 2; ++c)
#pragma unroll
            for (int rt = 0; rt < 2; ++rt)
#pragma unroll
                for (int i = 0; i < 4; ++i) {
                    int row = rt * 16 + ((lane >> 4) << 2) + i;
                    int cl  = c * 16 + (lane & 15);
                    short h, lo;
                    split2(aq[rt][c][i], h, lo);
                    Qh[row * PH + cl] = h; Qh[HL + row * PH + cl] = lo;
                    split2(ak[rt][c][i], h, lo);
                    Kh[row * PH + cl] = h; Kh[HL + row * PH + cl] = lo;
                }
        __syncthreads();   // all waves done reading Ab (QKV) before attn-O overwrites it

        // ---- attention (one head per wave, bf16x3; R3 op order) ----
        {
            f32x4 sA[2][2] = {};
            short8 qh[2], ql[2], kh[2], kl[2];
#pragma unroll
            for (int rt = 0; rt < 2; ++rt) {
                int byte = (rt * 16 + (lane & 15)) * (PH * 2) + ((lane >> 4) << 4);
                qh[rt] = *(const short8*)((const char*)Qh + byte);
                ql[rt] = *(const short8*)((const char*)Qh + HL * 2 + byte);
            }
#pragma unroll
            for (int ct = 0; ct < 2; ++ct) {
                int byte = (ct * 16 + (lane & 15)) * (PH * 2) + ((lane >> 4) << 4);
                kh[ct] = *(const short8*)((const char*)Kh + byte);
                kl[ct] = *(const short8*)((const char*)Kh + HL * 2 + byte);
            }
#pragma unroll
            for (int ct = 0; ct < 2; ++ct)
#pragma unroll
                for (int rt = 0; rt < 2; ++rt) {
                    sA[rt][ct] = MFMA(qh[rt], kh[ct], sA[rt][ct]);
                    sA[rt][ct] = MFMA(ql[rt], kh[ct], sA[rt][ct]);
                    sA[rt][ct] = MFMA(qh[rt], kl[ct], sA[rt][ct]);
                }

            // V: register transpose acc-layout -> PV B-fragment layout.
            // Shuffle BOTH rt candidates; select by DESTINATION half. Value-exact.
            short8 vbh[2], vbl[2];
#pragma unroll
            for (int ct = 0; ct < 2; ++ct)
#pragma unroll
                for (int j = 0; j < 8; ++j) {
                    int srcl = ((((lane >> 4) & 1) * 2 + (j >> 2)) << 4) | (lane & 15);
                    float v0 = __shfl(av[0][ct][j & 3], srcl);
                    float v1 = __shfl(av[1][ct][j & 3], srcl);
                    float vv = (lane < 32) ? v0 : v1;
                    short h, lo;
                    split2(vv, h, lo);
                    vbh[ct][j] = h; vbl[ct][j] = lo;
                }

            // row softmax -> P into QP tile (hi/lo); in-wave DS ordering (R3 construct)
#pragma unroll
            for (int rt = 0; rt < 2; ++rt)
#pragma unroll
                for (int i = 0; i < 4; ++i) {
                    float v0 = sA[rt][0][i] * scale, v1 = sA[rt][1][i] * scale;
                    float mx = fmaxf(v0, v1);
                    mx = fmaxf(mx, __shfl_xor(mx, 1));
                    mx = fmaxf(mx, __shfl_xor(mx, 2));
                    mx = fmaxf(mx, __shfl_xor(mx, 4));
                    mx = fmaxf(mx, __shfl_xor(mx, 8));
                    float e0 = __expf(v0 - mx), e1 = __expf(v1 - mx);
                    float sm = e0 + e1;
                    sm += __shfl_xor(sm, 1);
                    sm += __shfl_xor(sm, 2);
                    sm += __shfl_xor(sm, 4);
                    sm += __shfl_xor(sm, 8);
                    float inv = 1.0f / sm;
                    int row = rt * 16 + ((lane >> 4) << 2) + i;
                    short h, lo;
                    split2(e0 * inv, h, lo);
                    Qh[row * PH + (lane & 15)] = h;
                    Qh[HL + row * PH + (lane & 15)] = lo;
                    split2(e1 * inv, h, lo);
                    Qh[row * PH + 16 + (lane & 15)] = h;
                    Qh[HL + row * PH + 16 + (lane & 15)] = lo;
                }

            // O = P @ V  (P from QP tile, V from registers)
            f32x4 oA[2][2] = {};
            short8 ph[2], pl[2];
#pragma unroll
            for (int rt = 0; rt < 2; ++rt) {
                int byte = (rt * 16 + (lane & 15)) * (PH * 2) + ((lane >> 4) << 4);
                ph[rt] = *(const short8*)((const char*)Qh + byte);
                pl[rt] = *(const short8*)((const char*)Qh + HL * 2 + byte);
            }
#pragma unroll
            for (int ct = 0; ct < 2; ++ct)
#pragma unroll
                for (int rt = 0; rt < 2; ++rt) {
                    oA[rt][ct] = MFMA(ph[rt], vbh[ct], oA[rt][ct]);
                    oA[rt][ct] = MFMA(pl[rt], vbh[ct], oA[rt][ct]);
                    oA[rt][ct] = MFMA(ph[rt], vbl[ct], oA[rt][ct]);
                }

            // O -> Ab (hi/lo swizzled); head w owns cols [32w,32w+32)
#pragma unroll
            for (int rt = 0; rt < 2; ++rt)
#pragma unroll
                for (int ct = 0; ct < 2; ++ct)
#pragma unroll
                    for (int i = 0; i < 4; ++i) {
                        int row  = rt * 16 + ((lane >> 4) << 2) + i;
                        int colg = w * 32 + ct * 16 + (lane & 15);
                        int byte = (row * 256 + colg * 2) ^ ((row & 7) << 4);
                        short h, lo;
                        split2(oA[rt][ct][i], h, lo);
                        *(short*)((char*)AbH + byte) = h;
                        *(short*)((char*)AbL + byte) = lo;
                    }
        }
        __syncthreads();

        // x += O @ Wo
        {
            f32x4 ac[2][2] = {};
            mfma_gemm3<4>(AbH, AbL, WL + 3 * 16384 + w * 4096, ac, lane);
#pragma unroll
            for (int c = 0; c < 2; ++c) {
                int colg = w * 32 + c * 16 + (lane & 15);
#pragma unroll
                for (int rt = 0; rt < 2; ++rt)
#pragma unroll
                    for (int i = 0; i < 4; ++i) {
                        int row = rt * 16 + ((lane >> 4) << 2) + i;
                        X[row * PXF + colg] += ac[rt][c][i];
                    }
            }
        }
        __syncthreads();

        // LN2 -> Ab
        ln_to_Ab(X, ln2_s + l * DIM, ln2_b + l * DIM, AbH, AbL, t);
        __syncthreads();

        // FFN in 4 chunks of 128 ff-dims (Fb aliases K tiles; phases barrier-separated)
        for (int c4 = 0; c4 < 4; ++c4) {
            {
                f32x4 f1[2][2] = {};
                mfma_gemm3<4>(AbH, AbL, WL + (4 + c4) * 16384 + w * 4096, f1, lane);
#pragma unroll
                for (int c = 0; c < 2; ++c) {
                    int colg = w * 32 + c * 16 + (lane & 15);
                    float bv = b1[l * DFF + c4 * 128 + colg];
#pragma unroll
                    for (int rt = 0; rt < 2; ++rt)
#pragma unroll
                        for (int i = 0; i < 4; ++i) {
                            int row  = rt * 16 + ((lane >> 4) << 2) + i;
                            float v  = fmaxf(f1[rt][c][i] + bv, 0.0f);
                            int byte = (row * 256 + colg * 2) ^ ((row & 7) << 4);
                            short h, lo;
                            split2(v, h, lo);
                            *(short*)((char*)FbH + byte) = h;
                            *(short*)((char*)FbL + byte) = lo;
                        }
                }
            }
            __syncthreads();
            {
                f32x4 f2a[2][2] = {};
                mfma_gemm3<4>(FbH, FbL, WL + (8 + c4) * 16384 + w * 4096, f2a, lane);
#pragma unroll
                for (int c = 0; c < 2; ++c) {
                    int colg = w * 32 + c * 16 + (lane & 15);
                    float bv = (c4 == 0) ? b2[l * DIM + colg] : 0.0f;
#pragma unroll
                    for (int rt = 0; rt < 2; ++rt)
#pragma unroll
                        for (int i = 0; i < 4; ++i) {
                            int row = rt * 16 + ((lane >> 4) << 2) + i;
                            X[row * PXF + colg] += f2a[rt][c][i] + bv;
                        }
                }
            }
            __syncthreads();
        }
    }

    // ---- pooling logits ----
    {
        const int s = t >> 3, p = t & 7;
        float acc = 0.f;
        const float* row = X + s * PXF + p * 16;
        const float* wp = w_pool + p * 16;
#pragma unroll
        for (int j = 0; j < 16; ++j) acc = fmaf(row[j], wp[j], acc);
#pragma unroll
        for (int off = 1; off < 8; off <<= 1) acc += __shfl_xor(acc, off);
        if (p == 0) LG[s] = acc;
    }
    __syncthreads();
    if (t < DIM) {
        float m = -1e30f;
        for (int s = 0; s < NSEG; ++s) m = fmaxf(m, LG[s]);
        float ssum = 0.f;
        for (int s = 0; s < NSEG; ++s) ssum += __expf(LG[s] - m);
        float inv = 1.0f / ssum;
        float acc = 0.f;
        for (int s = 0; s < NSEG; ++s) acc = fmaf(__expf(LG[s] - m), X[s * PXF + t], acc);
        POOL[t] = acc * inv;
    }
    {
        const int s = t >> 3, p = t & 7;
        float c = 0.f, v = 0.f;
        const float* row = X + s * PXF + p * 16;
#pragma unroll
        for (int j = 0; j < 16; ++j) {
            float x = row[j];
            c = fmaf(x, W_dc[p * 16 + j], c);
            v = fmaf(x, W_dv[p * 16 + j], v);
        }
#pragma unroll
        for (int off = 1; off < 8; off <<= 1) { c += __shfl_xor(c, off); v += __shfl_xor(v, off); }
        if (p == 0) {
            SCC[s] = c + b_dc[0];
            SCV[s] = fminf(fmaxf(v + b_dv[0], 0.0f), 1.0f);
        }
    }
    __syncthreads();
    if (t < 64) {
        float v = POOL[t] * W_hit[t] + POOL[t + 64] * W_hit[t + 64];
#pragma unroll
        for (int off = 1; off < 64; off <<= 1) v += __shfl_xor(v, off);
        if (t == 0) {
            float hv = v + b_hit[0];
            out[ray] = (n_left == 0) ? -100.0f : hv;
        }
    }
    if (t == 255) {
        float best = -1e30f; int am = 0;
        for (int s = 0; s < NSEG; ++s) {
            if (s < n_left) {
                float cv = SCC[s];
                if (cv > best) { best = cv; am = s; }
            }
        }
        out[NRAYS + ray] = SCV[am] + (float)am * SEGL + t1;
    }
}

extern "C" void kernel_launch(void* const* d_in, const int* in_sizes, int n_in,
                              void* d_out, int out_size, void* d_ws, size_t ws_size,
                              hipStream_t stream) {
    (void)in_sizes; (void)n_in; (void)ws_size; (void)out_size;
    const float* points = (const float*)d_in[0];
    const float* W_up   = (const float*)d_in[1];
    const float* b_up   = (const float*)d_in[2];
    const float* ln1_s  = (const float*)d_in[3];
    const float* ln1_b  = (const float*)d_in[4];
    const float* Wq     = (const float*)d_in[5];
    const float* Wk     = (const float*)d_in[6];
    const float* Wv     = (const float*)d_in[7];
    const float* Wo     = (const float*)d_in[8];
    const float* ln2_s  = (const float*)d_in[9];
    const float* ln2_b  = (const float*)d_in[10];
    const float* W1     = (const float*)d_in[11];
    const float* b1     = (const float*)d_in[12];
    const float* W2     = (const float*)d_in[13];
    const float* b2     = (const float*)d_in[14];
    const float* w_pool = (const float*)d_in[15];
    const float* W_hit  = (const float*)d_in[16];
    const float* b_hit  = (const float*)d_in[17];
    const float* W_dc   = (const float*)d_in[18];
    const float* b_dc   = (const float*)d_in[19];
    const float* W_dv   = (const float*)d_in[20];
    const float* b_dv   = (const float*)d_in[21];
    short* Wf = (short*)d_ws;
    float* out = (float*)d_out;

    hipLaunchKernelGGL(prep_weights, dim3(1584), dim3(256), 0, stream,
                       W_up, Wq, Wk, Wv, Wo, W1, W2, Wf);
    hipLaunchKernelGGL(ray_tf_kernel, dim3(NRAYS / 2), dim3(512), 0, stream,
                       points, b_up, ln1_s, ln1_b, ln2_s, ln2_b, b1, b2, w_pool,
                       W_hit, b_hit, W_dc, b_dc, W_dv, b_dv, Wf, out);
}